// Round 4
// baseline (230.932 us; speedup 1.0000x reference)
//
#include <hip/hip_runtime.h>

#define DEV __device__ __forceinline__

constexpr int A_ = 64, DE = 128, M_ = 512, DH = 64;

DEV float wred_sum64(float v) {
#pragma unroll
    for (int o = 1; o < 64; o <<= 1) v += __shfl_xor(v, o, 64);
    return v;
}

// ---------------- Kernel 1: per-(b,m) hyperbolic dH2 + log_map ----------------
__global__ __launch_bounds__(256) void k_hyp(const float* __restrict__ curr_hyp,
                                             const float* __restrict__ demo_hyp,
                                             float* __restrict__ dH2,
                                             float* __restrict__ logv) {
    const int lane = threadIdx.x & 63;
    const int r    = (blockIdx.x << 2) + (threadIdx.x >> 6);  // [0, B*M)
    const int b    = r >> 9;                                  // M=512

    float x = curr_hyp[(b << 6) + lane];
    float y = demo_hyp[((size_t)r << 6) + lane];
    const float mx = 1.0f - 1e-5f;

    float x2r = wred_sum64(x * x);
    float xn  = fmaxf(sqrtf(x2r), 1e-15f);
    float sx  = xn > mx ? mx / xn : 1.0f;
    x *= sx;
    float x2 = x2r * sx * sx;
    float y2r = wred_sum64(y * y);
    float yn  = fmaxf(sqrtf(y2r), 1e-15f);
    float sy  = yn > mx ? mx / yn : 1.0f;
    y *= sy;
    float y2 = y2r * sy * sy;

    float xy = wred_sum64(x * y);
    float num = (1.f - 2.f * xy + y2) * (-x) + (1.f - x2) * y;
    float den = fmaxf(1.f - 2.f * xy + x2 * y2, 1e-15f);
    float u   = num / den;

    float u2  = wred_sum64(u * u);
    float un  = fmaxf(sqrtf(u2), 1e-15f);
    float arg = fminf(un, 1.f - 1e-7f);
    float at  = 0.5f * __logf((1.f + arg) / (1.f - arg));  // atanh

    if (lane == 0) dH2[r] = 4.f * at * at;

    float lamden = fmaxf(1.f - x2, 1e-15f);  // 2/lambda
    float ls     = lamden * at / un;
    logv[((size_t)r << 6) + lane] = ls * u;
}

// ---------------- Kernel 2: fused attention, barrier-free streaming ----------------
// one block per (b,a); 512 threads = 8 waves. Wave wv owns m in [wv*64, wv*64+64).
// lane: dp = lane&15 (de dims dp*8..dp*8+8), mq = lane>>4; lane's m-set: {wv*64+mq+4i}.
// Per-lane online softmax state (mx, sm, ac[8]); shuffle-merge; ONE joining barrier.
__global__ __launch_bounds__(512, 4) void k_main(const float* __restrict__ curr_rho,
                                                 const float* __restrict__ demo_rho,
                                                 const float* __restrict__ curr_hyp,
                                                 const float* __restrict__ dH2,
                                                 const float* __restrict__ logv,
                                                 const float* __restrict__ We,
                                                 const float* __restrict__ Wh,
                                                 const float* __restrict__ gamma,
                                                 const float* __restrict__ beta,
                                                 float* __restrict__ out) {
    __shared__ float lds_sc[512];
    __shared__ float lds_dh[512];
    __shared__ float redmax[8];
    __shared__ float redsum[8];
    __shared__ __align__(16) float accbuf[8 * 132];
    __shared__ float vpart[8][64];
    __shared__ float eh[192];  // [0:128) e_out, [128:192) h

    const int t    = threadIdx.x;
    const int lane = t & 63;
    const int wv   = t >> 6;
    const int dp   = lane & 15;
    const int mq   = lane >> 4;
    const int blk  = blockIdx.x;
    const int b    = blk >> 6, a = blk & 63;

    // wave wv writes lds_dh[wv*64 .. wv*64+64) and reads only that range: no barrier needed
    lds_dh[t] = dH2[(b << 9) + t];

    float qf[8];
    {
        float4 q0 = *(const float4*)(curr_rho + (size_t)blk * DE + dp * 8);
        float4 q1 = *(const float4*)(curr_rho + (size_t)blk * DE + dp * 8 + 4);
        qf[0] = q0.x; qf[1] = q0.y; qf[2] = q0.z; qf[3] = q0.w;
        qf[4] = q1.x; qf[5] = q1.y; qf[6] = q1.z; qf[7] = q1.w;
    }

    const size_t rowStride = (size_t)A_ * DE;  // 8192 floats
    // demo[b][m][a][d]: lane's first m = wv*64 + mq
    const float* p = demo_rho + (((size_t)b * M_ + wv * 64 + mq) * A_ + a) * DE + dp * 8;

    float mx = -1e30f, sm = 0.f, ac[8];
#pragma unroll
    for (int j = 0; j < 8; j++) ac[j] = 0.f;

    float4 c0 = *(const float4*)p;
    float4 c1 = *(const float4*)(p + 4);

    for (int i = 0; i < 16; ++i) {
        const float* pn = p + 4 * rowStride;
        float4 n0, n1;
        if (i < 15) { n0 = *(const float4*)pn; n1 = *(const float4*)(pn + 4); }

        float kf[8];
        kf[0] = c0.x; kf[1] = c0.y; kf[2] = c0.z; kf[3] = c0.w;
        kf[4] = c1.x; kf[5] = c1.y; kf[6] = c1.z; kf[7] = c1.w;

        float ps = 0.f;
#pragma unroll
        for (int j = 0; j < 8; j++) { float d = qf[j] - kf[j]; ps = fmaf(d, d, ps); }
        ps += __shfl_xor(ps, 1, 64);
        ps += __shfl_xor(ps, 2, 64);
        ps += __shfl_xor(ps, 4, 64);
        ps += __shfl_xor(ps, 8, 64);  // uniform over the 16 dp lanes

        const int ml = wv * 64 + mq + 4 * i;
        float sc = -(lds_dh[ml] + ps);
        if (dp == 0) lds_sc[ml] = sc;

        // per-lane online update
        float nm = fmaxf(mx, sc);
        float r  = __expf(mx - nm);   // first iter: exp(-huge)=0
        float w  = __expf(sc - nm);
        sm = sm * r + w;
#pragma unroll
        for (int j = 0; j < 8; j++) ac[j] = fmaf(ac[j], r, w * kf[j]);
        mx = nm;

        p = pn; c0 = n0; c1 = n1;
    }

    // merge the 4 mq-groups (xor 16, 32); dp stays aligned so ac dims match
#pragma unroll
    for (int off = 16; off < 64; off <<= 1) {
        float mxo = __shfl_xor(mx, off, 64);
        float smo = __shfl_xor(sm, off, 64);
        float aco[8];
#pragma unroll
        for (int j = 0; j < 8; j++) aco[j] = __shfl_xor(ac[j], off, 64);
        float nm = fmaxf(mx, mxo);
        float r1 = __expf(mx - nm), r2 = __expf(mxo - nm);
        sm = sm * r1 + smo * r2;
#pragma unroll
        for (int j = 0; j < 8; j++) ac[j] = ac[j] * r1 + aco[j] * r2;
        mx = nm;
    }
    if (lane == 0) { redmax[wv] = mx; redsum[wv] = sm; }
    __syncthreads();  // the ONE joining barrier for stream results

    float gmax = redmax[0];
#pragma unroll
    for (int w = 1; w < 8; w++) gmax = fmaxf(gmax, redmax[w]);
    float gsum = 0.f;
#pragma unroll
    for (int w = 0; w < 8; w++) gsum += redsum[w] * __expf(redmax[w] - gmax);
    const float inv = 1.f / gsum;  // block-uniform

    // rescaled wave accumulators -> LDS
    float resc = __expf(mx - gmax);  // mx is wave-uniform now
    if (lane < 16) {
        *(float4*)&accbuf[wv * 132 + dp * 8] =
            make_float4(ac[0] * resc, ac[1] * resc, ac[2] * resc, ac[3] * resc);
        *(float4*)&accbuf[wv * 132 + dp * 8 + 4] =
            make_float4(ac[4] * resc, ac[5] * resc, ac[6] * resc, ac[7] * resc);
    }

    // v = alpha @ logv : wave wv handles its own m-range (lds_sc same-wave visible)
    {
        const float* lvb = logv + ((size_t)(b * M_) + wv * 64) * DH;
        float vacc = 0.f;
#pragma unroll 8
        for (int i = 0; i < 64; ++i) {
            float al = __expf(lds_sc[wv * 64 + i] - gmax);
            vacc = fmaf(al, lvb[(size_t)i * DH + lane], vacc);
        }
        vpart[wv][lane] = vacc * inv;
    }
    __syncthreads();

    if (t < 128) {
        float s = 0.f;
#pragma unroll
        for (int g = 0; g < 8; g++) s += accbuf[g * 132 + t];
        eh[t] = s * inv;
    }
    __syncthreads();

    if (wv == 0) {
        float v = 0.f;
#pragma unroll
        for (int w = 0; w < 8; w++) v += vpart[w][lane];

        const float mxb = 1.0f - 1e-5f;
        float x = curr_hyp[(b << 6) + lane];
        float x2r = wred_sum64(x * x);
        float xn  = fmaxf(sqrtf(x2r), 1e-15f);
        float sx  = xn > mxb ? mxb / xn : 1.f;
        x *= sx;
        float x2 = x2r * sx * sx;
        float lamden = fmaxf(1.f - x2, 1e-15f);  // 2/lambda

        float v2 = wred_sum64(v * v);
        float vn = fmaxf(sqrtf(v2), 1e-15f);
        float targ   = vn / lamden;              // lambda*vnorm/2
        float e2     = __expf(2.f * targ);
        float factor = 1.f - 2.f / (e2 + 1.f);   // tanh, inf-safe
        float wvv    = v * (factor / vn);

        float w2 = wred_sum64(wvv * wvv);
        float xw = wred_sum64(x * wvv);
        float num = (1.f + 2.f * xw + w2) * x + (1.f - x2) * wvv;
        float den = fmaxf(1.f + 2.f * xw + x2 * w2, 1e-15f);
        float h   = num / den;
        float h2  = wred_sum64(h * h);
        float hn  = fmaxf(sqrtf(h2), 1e-15f);
        float shh = hn > mxb ? mxb / hn : 1.f;
        h *= shh;
        eh[128 + lane] = h;  // same-wave visibility

        float ze = 0.f;
        const float* werow = We + lane * 128;
#pragma unroll
        for (int d0 = 0; d0 < 128; d0 += 4) {
            float4 wv4 = *(const float4*)(werow + d0);
            ze = fmaf(eh[d0 + 0], wv4.x, ze);
            ze = fmaf(eh[d0 + 1], wv4.y, ze);
            ze = fmaf(eh[d0 + 2], wv4.z, ze);
            ze = fmaf(eh[d0 + 3], wv4.w, ze);
        }
        float zh = 0.f;
        const float* whrow = Wh + lane * 64;
#pragma unroll
        for (int d0 = 0; d0 < 64; d0 += 4) {
            float4 wv4 = *(const float4*)(whrow + d0);
            zh = fmaf(eh[128 + d0 + 0], wv4.x, zh);
            zh = fmaf(eh[128 + d0 + 1], wv4.y, zh);
            zh = fmaf(eh[128 + d0 + 2], wv4.z, zh);
            zh = fmaf(eh[128 + d0 + 3], wv4.w, zh);
        }
        float ssum = wred_sum64(ze + zh);
        float mean = ssum * (1.f / 128.f);
        float sq   = wred_sum64(ze * ze + zh * zh);
        float var  = sq * (1.f / 128.f) - mean * mean;
        float rinv = rsqrtf(var + 1e-5f);
        float oe = (ze - mean) * rinv * gamma[lane] + beta[lane];
        float oh = (zh - mean) * rinv * gamma[64 + lane] + beta[64 + lane];
        out[(size_t)blk * 128 + lane]      = oe;
        out[(size_t)blk * 128 + 64 + lane] = oh;
    }
}

extern "C" void kernel_launch(void* const* d_in, const int* in_sizes, int n_in,
                              void* d_out, int out_size, void* d_ws, size_t ws_size,
                              hipStream_t stream) {
    const float* curr_rho = (const float*)d_in[0];
    const float* curr_hyp = (const float*)d_in[1];
    const float* demo_rho = (const float*)d_in[2];
    const float* demo_hyp = (const float*)d_in[3];
    const float* We       = (const float*)d_in[4];
    const float* Wh       = (const float*)d_in[5];
    const float* gamma    = (const float*)d_in[6];
    const float* beta     = (const float*)d_in[7];
    float* out = (float*)d_out;

    float* ws   = (float*)d_ws;
    float* dH2  = ws;            // 4096 floats
    float* logv = ws + 4096;     // 262144 floats

    k_hyp<<<1024, 256, 0, stream>>>(curr_hyp, demo_hyp, dH2, logv);
    k_main<<<512, 512, 0, stream>>>(curr_rho, demo_rho, curr_hyp, dH2, logv,
                                    We, Wh, gamma, beta, out);
}